// Round 9
// baseline (276.726 us; speedup 1.0000x reference)
//
#include <hip/hip_runtime.h>
#include <math.h>

#define IC 64
#define OC 16
#define DIM 64

typedef __attribute__((ext_vector_type(8))) short bf16x8;
typedef __attribute__((ext_vector_type(4))) float f32x4;

__device__ __forceinline__ unsigned short f2bf(float f) { // RNE float->bf16
    unsigned int b = __float_as_uint(f);
    b += 0x7fffu + ((b >> 16) & 1u);
    return (unsigned short)(b >> 16);
}
__device__ __forceinline__ float bf2f(unsigned short h) {
    return __uint_as_float(((unsigned int)h) << 16);
}

// ---------------------------------------------------------------------------
// kF1: fused {setup | kT | kA}. Blocks 0..255 setup, 256..2303 kT, 2304..6399
// kA (btile = ba&63, i = ba>>6). No cross-role dependencies inside the launch.
// R8 change: kA-role B-panel staging uses a 16B-slot XOR swizzle
// (slot' = slot ^ ((row>>1)&7)) on BOTH the transpose-scatter writes and the
// bf16x8 reads. Removes the 4-way ds_write_b16 bank conflicts (q-groups
// collided: row-step 4*144B == 0 mod 128B). Write banks now disjoint across
// q (2 lanes/bank = free, m136); read slot permutation bijective per row.
// (R9 attempt history: cooperative kLoop fusion REJECTED at launch — output
// never written; launch boundaries must stay.)
// ---------------------------------------------------------------------------
__global__ __launch_bounds__(256, 4)
void kF1(const float* __restrict__ W_F2, const float* __restrict__ W_S,
         const float* __restrict__ B_S, const float* __restrict__ bu,
         const float* __restrict__ bi_, const float* __restrict__ W_G1,
         const float* __restrict__ W_G2, const float* __restrict__ W_F1,
         const float* __restrict__ x, const float* __restrict__ W_A,
         const float* __restrict__ B_A,
         float* __restrict__ WSt2,
         unsigned short* __restrict__ W1h, unsigned short* __restrict__ W1l,
         unsigned short* __restrict__ W2h, unsigned short* __restrict__ W2l,
         float* __restrict__ BSt, float* __restrict__ cb, float* __restrict__ db,
         float* __restrict__ xq, float* __restrict__ fa, float* __restrict__ phi,
         float* __restrict__ tF)
{
    __shared__ __align__(16) unsigned char raw[36864];
    const int bx = blockIdx.x;
    const int t = threadIdx.x;

    if (bx < 256) { // ---- setup role ----
        int e = bx * 256 + t; // 0..65535
        { // W1: B^T of W_F2 panel, bf16 hi/lo
            int h = e >> 10, m = (e >> 6) & 15, d = e & 63;
            float v = W_F2[((size_t)m * 64 + h) * 64 + d];
            unsigned short hh = f2bf(v);
            size_t o = ((size_t)m * 64 + d) * 64 + h;
            W1h[o] = hh; W1l[o] = f2bf(v - bf2f(hh));
        }
        {
            int m = e >> 12, fo = (e >> 8) & 15, i = (e >> 2) & 63, fi = e & 3;
            WSt2[e] = W_S[((size_t)i * 16 + m) * 64 + fo * 4 + fi];
        }
        { // WG12[m][d][f] computed locally, stored transposed as W2[m][f][d]
            int m = e >> 12, d = (e >> 6) & 63, f = e & 63;
            const float* g1 = W_G1 + d * 64;
            const float* g2 = W_G2 + (size_t)m * 4096 + f;
            float a = 0.f;
#pragma unroll 8
            for (int h = 0; h < 64; h++) a += g1[h] * g2[h * 64];
            unsigned short hh = f2bf(a);
            size_t o = ((size_t)m * 64 + f) * 64 + d;
            W2h[o] = hh; W2l[o] = f2bf(a - bf2f(hh));
        }
        if (e < 1024) {
            int m = e >> 6, i = e & 63;
            BSt[e] = B_S[i * 16 + m];
            cb[e] = bu[e] + bi_[e];
        }
        if (e < 64) {
            float sd = 0.f;
            for (int m = 0; m < 16; m++) sd += bi_[e * 16 + m];
            db[e] = sd;
        }
        return;
    }

    if (bx < 2304) { // ---- kT role: x pass -> xq; fa/phi0 ----
        float* Xs = (float*)raw; // [2*64*65] = 33280 B
        const int blk = bx - 256;

        const float4* x4 = (const float4*)x;
#pragma unroll
        for (int s = 0; s < 8; s++) { // stage 2 batch rows, 1KB/instr coalesced
            int p = s * 256 + t;
            float4 v = x4[(size_t)blk * 2048 + p];
            int b = p >> 10, i = (p >> 4) & 63, fo = p & 15;
            float* row = &Xs[(b * 64 + i) * 65 + fo * 4];
            row[0] = v.x; row[1] = v.y; row[2] = v.z; row[3] = v.w;
        }
        __syncthreads();

        const int lane = t & 63, w = t >> 6;
#pragma unroll
        for (int s = 0; s < 8; s++) { // xq: lane=i, coalesced 1KB writes
            int idx = s * 4 + w;
            int b = idx >> 4, fo = idx & 15;
            const float* row = &Xs[(b * 64 + lane) * 65 + fo * 4];
            ((float4*)xq)[((size_t)(blk * 2 + b) * 16 + fo) * 64 + lane] =
                make_float4(row[0], row[1], row[2], row[3]);
        }

        { // fa/phi: pair p=(b,i), half h sums 32 f's
            int p = t >> 1, h = t & 1;
            int b = p >> 6, i = p & 63;
            const float* row = &Xs[(b * 64 + i) * 65 + h * 32];
            const float* wa = W_A + i * 64 + h * 32;
            float v = 0.f;
#pragma unroll
            for (int j = 0; j < 32; j++) v += row[j] * wa[j];
            v += __shfl_xor(v, 1);
            if (h == 0) {
                // eb[i] recomputed locally (bu/bi_ are L1/L2-hot, 8 KB total)
                float sc = 0.f, sd = 0.f;
                for (int m = 0; m < 16; m++) {
                    float vu = bu[i * 16 + m], vi = bi_[i * 16 + m];
                    sc += vu + vi; sd += vi;
                }
                float ebi = sc * (1.0f / 16.0f) - sd;
                float ae = v * 0.125f + B_A[i];
                float fv = 1.0f / (1.0f + expf(-ae));
                size_t o = (size_t)(blk * 2 + b) * 64 + i;
                fa[o] = fv;
                phi[o] = fv * ebi;
            }
        }
        return;
    }

    // ---- kA role (MFMA bf16x3): tF[b][i][h] = (x[b][i][:] @ W_F1[i]) * 0.125
    {
        unsigned short* Ah = (unsigned short*)raw; // [64][72] hi
        unsigned short* Al = Ah + 64 * 72;         // lo
        unsigned short* Bh = Al + 64 * 72;         // B^T hi (slot-swizzled)
        unsigned short* Bl = Bh + 64 * 72;         // B^T lo (slot-swizzled)
        const int ba = bx - 2304;
        const int b0 = (ba & 63) * 64;
        const int i = ba >> 6;
        const int bl = t >> 2, q = t & 3;

        { // stage X rows -> Ah/Al (split); W_F1 -> Bh/Bl (transpose+split+swz)
            const float* src = x + ((size_t)(b0 + bl) * IC + i) * DIM + q * 4;
#pragma unroll
            for (int j4 = 0; j4 < 4; j4++) {
                float4 v = *(const float4*)(src + j4 * 16);
                int f = q * 4 + j4 * 16;
                float vv[4] = {v.x, v.y, v.z, v.w};
                ushort4 h4, l4;
                unsigned short hh;
                hh = f2bf(vv[0]); h4.x = hh; l4.x = f2bf(vv[0] - bf2f(hh));
                hh = f2bf(vv[1]); h4.y = hh; l4.y = f2bf(vv[1] - bf2f(hh));
                hh = f2bf(vv[2]); h4.z = hh; l4.z = f2bf(vv[2] - bf2f(hh));
                hh = f2bf(vv[3]); h4.w = hh; l4.w = f2bf(vv[3] - bf2f(hh));
                *(ushort4*)&Ah[bl * 72 + f] = h4;
                *(ushort4*)&Al[bl * 72 + f] = l4;
            }
            const float* wsrc = W_F1 + ((size_t)i * DIM + bl) * DIM + q * 4;
#pragma unroll
            for (int j4 = 0; j4 < 4; j4++) {
                float4 v = *(const float4*)(wsrc + j4 * 16);
                int h0 = q * 4 + j4 * 16;
                float vv[4] = {v.x, v.y, v.z, v.w};
#pragma unroll
                for (int c = 0; c < 4; c++) {
                    int row = h0 + c; // B^T row = h, col = bl (= f)
                    // 16B-slot swizzle: slot' = (col>>3) ^ ((row>>1)&7)
                    int idx = row * 72 +
                              ((((bl >> 3) ^ ((row >> 1) & 7)) << 3)) + (bl & 7);
                    unsigned short hh = f2bf(vv[c]);
                    Bh[idx] = hh;
                    Bl[idx] = f2bf(vv[c] - bf2f(hh));
                }
            }
        }
        __syncthreads();

        const int w = t >> 6, lane = t & 63;
        const int fm = lane & 15, fq = lane >> 4;
        const int r0 = w * 16;
        f32x4 acc[4];
#pragma unroll
        for (int nt = 0; nt < 4; nt++) {
            acc[nt][0] = 0.f; acc[nt][1] = 0.f; acc[nt][2] = 0.f; acc[nt][3] = 0.f;
        }

#pragma unroll
        for (int ks = 0; ks < 2; ks++) {
            const int kk = ks * 32 + fq * 8;
            bf16x8 ah = *(const bf16x8*)&Ah[(r0 + fm) * 72 + kk];
            bf16x8 al = *(const bf16x8*)&Al[(r0 + fm) * 72 + kk];
#pragma unroll
            for (int nt = 0; nt < 4; nt++) {
                int brow = nt * 16 + fm;
                int bo = brow * 72 +
                         ((((kk >> 3) ^ ((brow >> 1) & 7)) << 3)); // swz read
                bf16x8 bh = *(const bf16x8*)&Bh[bo];
                bf16x8 bl2 = *(const bf16x8*)&Bl[bo];
                acc[nt] = __builtin_amdgcn_mfma_f32_16x16x32_bf16(ah, bh, acc[nt], 0, 0, 0);
                acc[nt] = __builtin_amdgcn_mfma_f32_16x16x32_bf16(ah, bl2, acc[nt], 0, 0, 0);
                acc[nt] = __builtin_amdgcn_mfma_f32_16x16x32_bf16(al, bh, acc[nt], 0, 0, 0);
            }
        }

#pragma unroll
        for (int nt = 0; nt < 4; nt++)
#pragma unroll
            for (int j = 0; j < 4; j++) {
                int row = r0 + fq * 4 + j;
                int col = nt * 16 + fm;
                tF[((size_t)(b0 + row) * IC + i) * DIM + col] = acc[nt][j] * 0.125f;
            }
    }
}

// ---------------------------------------------------------------------------
// kS: s[b][h] = sum_i phi[b][i] * tF[b][i][h].  1024 blocks, wave per b.
// (iteration-0 only; later iterations fused into kC)
// ---------------------------------------------------------------------------
__global__ __launch_bounds__(256, 4)
void kS(const float* __restrict__ phi, const float* __restrict__ tF,
        float* __restrict__ s)
{
    __shared__ float ph[4 * 64];
    const int t = threadIdx.x;
    const int b0 = blockIdx.x * 4;
    ph[t] = phi[(size_t)b0 * 64 + t];
    __syncthreads();

    const int w = t >> 6, lane = t & 63;
    const int ig = lane >> 4, hq = lane & 15;
    const int b = b0 + w;
    const float4* tf4 = (const float4*)(tF + ((size_t)b * 64 + ig * 16) * 64) + hq;
    float4 a = make_float4(0.f, 0.f, 0.f, 0.f);
#pragma unroll
    for (int k = 0; k < 16; k++) {
        float p = ph[w * 64 + ig * 16 + k];
        float4 v = tf4[k * 16];
        a.x += p * v.x; a.y += p * v.y; a.z += p * v.z; a.w += p * v.w;
    }
#pragma unroll
    for (int k = 16; k <= 32; k <<= 1) {
        a.x += __shfl_xor(a.x, k); a.y += __shfl_xor(a.y, k);
        a.z += __shfl_xor(a.z, k); a.w += __shfl_xor(a.w, k);
    }
    if (ig == 0)
        ((float4*)(s + (size_t)b * 64))[hq] = a;
}

// ---------------------------------------------------------------------------
// kXG (MFMA bf16x3): per (b-tile 64, m): two chained GEMMs.
//  GEMM1: x_out = s @ W_F2[m] + B_F2[m]  (A=s split on the fly, B=W1 panel)
//  (last: write out, exit)  LN in-register (quad shfl), xnorm->LDS bf16 split
//  GEMM2: xhat = xnorm @ WG12[m] + B_G2[m]  (B=W2 panel)
// LDS: A(hi/lo) + B(hi/lo), both reused across the two GEMMs. 36.9 KB.
// ---------------------------------------------------------------------------
__global__ __launch_bounds__(256, 4)
void kXG(const float* __restrict__ s,
         const unsigned short* __restrict__ W1h, const unsigned short* __restrict__ W1l,
         const float* __restrict__ B_F2,
         const unsigned short* __restrict__ W2h, const unsigned short* __restrict__ W2l,
         const float* __restrict__ B_G2,
         const float* __restrict__ gam, const float* __restrict__ bet,
         float* __restrict__ xhat, float* __restrict__ out, const int last)
{
    __shared__ unsigned short Ah[64][72], Al[64][72]; // s then xnorm (hi/lo)
    __shared__ unsigned short Bh[64][72], Bl[64][72]; // W1^T then W2^T panels
    const int b0 = blockIdx.x * 64;
    const int m = blockIdx.y;
    const int t = threadIdx.x;
    const int bl = t >> 2, q = t & 3;

    { // stage s rows -> Ah/Al (split), W1 panel -> Bh/Bl (copy)
        const float* src = s + (size_t)(b0 + bl) * DIM + q * 16;
#pragma unroll
        for (int j4 = 0; j4 < 4; j4++) {
            float4 v = ((const float4*)src)[j4];
            int f = q * 16 + j4 * 4;
            float vv[4] = {v.x, v.y, v.z, v.w};
            ushort4 h4, l4;
            unsigned short hh;
            hh = f2bf(vv[0]); h4.x = hh; l4.x = f2bf(vv[0] - bf2f(hh));
            hh = f2bf(vv[1]); h4.y = hh; l4.y = f2bf(vv[1] - bf2f(hh));
            hh = f2bf(vv[2]); h4.z = hh; l4.z = f2bf(vv[2] - bf2f(hh));
            hh = f2bf(vv[3]); h4.w = hh; l4.w = f2bf(vv[3] - bf2f(hh));
            *(ushort4*)&Ah[bl][f] = h4;
            *(ushort4*)&Al[bl][f] = l4;
        }
        const size_t wo = ((size_t)m * 64 + bl) * 64 + q * 16;
#pragma unroll
        for (int part = 0; part < 2; part++) {
            *(uint4*)&Bh[bl][q * 16 + part * 8] = *(const uint4*)(W1h + wo + part * 8);
            *(uint4*)&Bl[bl][q * 16 + part * 8] = *(const uint4*)(W1l + wo + part * 8);
        }
    }
    __syncthreads();

    const int w = t >> 6, lane = t & 63;
    const int fm = lane & 15, fq = lane >> 4;
    const int r0 = w * 16;
    f32x4 acc[4];
#pragma unroll
    for (int nt = 0; nt < 4; nt++) {
        acc[nt][0] = 0.f; acc[nt][1] = 0.f; acc[nt][2] = 0.f; acc[nt][3] = 0.f;
    }
#pragma unroll
    for (int ks = 0; ks < 2; ks++) {
        const int kk = ks * 32 + fq * 8;
        bf16x8 ah = *(const bf16x8*)&Ah[r0 + fm][kk];
        bf16x8 al = *(const bf16x8*)&Al[r0 + fm][kk];
#pragma unroll
        for (int nt = 0; nt < 4; nt++) {
            bf16x8 bh = *(const bf16x8*)&Bh[nt * 16 + fm][kk];
            bf16x8 bl2 = *(const bf16x8*)&Bl[nt * 16 + fm][kk];
            acc[nt] = __builtin_amdgcn_mfma_f32_16x16x32_bf16(ah, bh, acc[nt], 0, 0, 0);
            acc[nt] = __builtin_amdgcn_mfma_f32_16x16x32_bf16(ah, bl2, acc[nt], 0, 0, 0);
            acc[nt] = __builtin_amdgcn_mfma_f32_16x16x32_bf16(al, bh, acc[nt], 0, 0, 0);
        }
    }
#pragma unroll
    for (int nt = 0; nt < 4; nt++) { // + B_F2[m]
        float bf = B_F2[m * DIM + nt * 16 + fm];
#pragma unroll
        for (int j = 0; j < 4; j++) acc[nt][j] += bf;
    }

    if (last) { // final x_out
#pragma unroll
        for (int nt = 0; nt < 4; nt++)
#pragma unroll
            for (int j = 0; j < 4; j++) {
                int row = r0 + fq * 4 + j;
                out[((size_t)(b0 + row) * OC + m) * DIM + nt * 16 + fm] = acc[nt][j];
            }
        return;
    }

    { // LayerNorm: row = b = r0+fq*4+j lives across 16 fm-lanes x 4 regs
        float g4[4], b4[4];
#pragma unroll
        for (int nt = 0; nt < 4; nt++) {
            g4[nt] = gam[nt * 16 + fm];
            b4[nt] = bet[nt * 16 + fm];
        }
#pragma unroll
        for (int j = 0; j < 4; j++) {
            float sum = acc[0][j] + acc[1][j] + acc[2][j] + acc[3][j];
            float sq = acc[0][j] * acc[0][j] + acc[1][j] * acc[1][j] +
                       acc[2][j] * acc[2][j] + acc[3][j] * acc[3][j];
#pragma unroll
            for (int k = 1; k <= 8; k <<= 1) {
                sum += __shfl_xor(sum, k);
                sq  += __shfl_xor(sq, k);
            }
            float mu = sum * (1.0f / 64.0f);
            float var = sq * (1.0f / 64.0f) - mu * mu;
            float rs = 1.0f / sqrtf(var + 1e-5f);
#pragma unroll
            for (int nt = 0; nt < 4; nt++)
                acc[nt][j] = (acc[nt][j] - mu) * rs * g4[nt] + b4[nt];
        }
    }
    __syncthreads(); // GEMM1 LDS reads complete before overwrite

    { // A <- xnorm (split, C-layout scatter); B <- W2 panel
#pragma unroll
        for (int nt = 0; nt < 4; nt++)
#pragma unroll
            for (int j = 0; j < 4; j++) {
                float v = acc[nt][j];
                unsigned short hh = f2bf(v);
                int row = r0 + fq * 4 + j, col = nt * 16 + fm;
                Ah[row][col] = hh;
                Al[row][col] = f2bf(v - bf2f(hh));
            }
        const size_t wo = ((size_t)m * 64 + bl) * 64 + q * 16;
#pragma unroll
        for (int part = 0; part < 2; part++) {
            *(uint4*)&Bh[bl][q * 16 + part * 8] = *(const uint4*)(W2h + wo + part * 8);
            *(uint4*)&Bl[bl][q * 16 + part * 8] = *(const uint4*)(W2l + wo + part * 8);
        }
    }
    __syncthreads();

    f32x4 xh[4];
#pragma unroll
    for (int nt = 0; nt < 4; nt++) {
        float bg = B_G2[m * DIM + nt * 16 + fm];
        xh[nt][0] = bg; xh[nt][1] = bg; xh[nt][2] = bg; xh[nt][3] = bg;
    }
#pragma unroll
    for (int ks = 0; ks < 2; ks++) {
        const int kk = ks * 32 + fq * 8;
        bf16x8 ah = *(const bf16x8*)&Ah[r0 + fm][kk];
        bf16x8 al = *(const bf16x8*)&Al[r0 + fm][kk];
#pragma unroll
        for (int nt = 0; nt < 4; nt++) {
            bf16x8 bh = *(const bf16x8*)&Bh[nt * 16 + fm][kk];
            bf16x8 bl2 = *(const bf16x8*)&Bl[nt * 16 + fm][kk];
            xh[nt] = __builtin_amdgcn_mfma_f32_16x16x32_bf16(ah, bh, xh[nt], 0, 0, 0);
            xh[nt] = __builtin_amdgcn_mfma_f32_16x16x32_bf16(ah, bl2, xh[nt], 0, 0, 0);
            xh[nt] = __builtin_amdgcn_mfma_f32_16x16x32_bf16(al, bh, xh[nt], 0, 0, 0);
        }
    }
#pragma unroll
    for (int nt = 0; nt < 4; nt++)
#pragma unroll
        for (int j = 0; j < 4; j++) {
            int row = r0 + fq * 4 + j;
            xhat[((size_t)(b0 + row) * OC + m) * DIM + nt * 16 + fm] = xh[nt][j];
        }
}

// ---------------------------------------------------------------------------
// kC: consistency + softmax + phi + NEXT-ITER s (fused kS). 4 b/block, 1024
// blocks, 256 threads — the measured equilibrium (39.6 us).
// Perturbations measured and rejected (the evidence list):
//  - 512t/4b (waves split g): +17% VMEM instrs -> 45.1us          (R1)
//  - scalar-pipe xhat (s_load): K$ thrash, FETCH +8MB -> 52.4us   (R2)
//  - 256t/2b x 2048 blocks: L2 thrash, FETCH 250MB -> 142us       (R3)
//  - uniform-addr global vector loads for xhat: latency-exposed,
//    VALUBusy 28% -> 60.4us                                       (R6)
//  - cooperative grid-sync fusion: launch rejected, no output     (R8)
// ---------------------------------------------------------------------------
__global__ __launch_bounds__(256, 4)
void kC(const float* __restrict__ xq, const float* __restrict__ xhat,
        const float* __restrict__ WSt2, const float* __restrict__ BSt,
        const float* __restrict__ cb, const float* __restrict__ db,
        const float* __restrict__ fa, const float* __restrict__ tF,
        float* __restrict__ s)
{
    __shared__ float buf[4 * 64 * 17]; // xhat view (4096) -> cons view (g*64+i)*17+m
    __shared__ float phs[4][64];
    const int b0 = blockIdx.x * 4;
    const int t = threadIdx.x;
    const int w = t >> 6, lane = t & 63;

    { // stage xhat[b0..b0+4): 4096 floats
        const float4* src = (const float4*)(xhat + (size_t)b0 * OC * DIM);
        float4* dst = (float4*)buf;
#pragma unroll
        for (int j = 0; j < 4; j++) dst[t + j * 256] = src[t + j * 256];
    }
    __syncthreads();

    float acc[4][4];
#pragma unroll
    for (int k = 0; k < 4; k++) {
        float bs = BSt[(w * 4 + k) * IC + lane];
#pragma unroll
        for (int g = 0; g < 4; g++) acc[g][k] = bs;
    }

    const float4* xq4 = (const float4*)xq;
    for (int fc = 0; fc < 64; fc += 8) {
        const int fo = fc >> 2;
        float wreg[4][8];
#pragma unroll
        for (int k = 0; k < 4; k++) {
            int m = w * 4 + k;
#pragma unroll
            for (int q2 = 0; q2 < 2; q2++) {
                float4 v = *(const float4*)&WSt2[(((size_t)m * 16 + fo + q2) * IC + lane) * 4];
                wreg[k][q2 * 4 + 0] = v.x; wreg[k][q2 * 4 + 1] = v.y;
                wreg[k][q2 * 4 + 2] = v.z; wreg[k][q2 * 4 + 3] = v.w;
            }
        }
#pragma unroll
        for (int g = 0; g < 4; g++) {
            float xr[8];
#pragma unroll
            for (int q2 = 0; q2 < 2; q2++) { // coalesced 1KB/instr
                float4 v = xq4[((size_t)(b0 + g) * 16 + fo + q2) * 64 + lane];
                xr[q2 * 4 + 0] = v.x; xr[q2 * 4 + 1] = v.y;
                xr[q2 * 4 + 2] = v.z; xr[q2 * 4 + 3] = v.w;
            }
#pragma unroll
            for (int k = 0; k < 4; k++) {
                int m = w * 4 + k;
                const float* hp = &buf[(g * OC + m) * DIM + fc];
                float hr[8];
#pragma unroll
                for (int q2 = 0; q2 < 2; q2++) { // same-addr broadcast reads
                    float4 v = *(const float4*)(hp + q2 * 4);
                    hr[q2 * 4 + 0] = v.x; hr[q2 * 4 + 1] = v.y;
                    hr[q2 * 4 + 2] = v.z; hr[q2 * 4 + 3] = v.w;
                }
#pragma unroll
                for (int ff = 0; ff < 8; ff++)
                    acc[g][k] += xr[ff] * hr[ff] * wreg[k][ff];
            }
        }
    }
    __syncthreads(); // all xhat reads done before overwrite
#pragma unroll
    for (int g = 0; g < 4; g++)
#pragma unroll
        for (int k = 0; k < 4; k++)
            buf[(g * IC + lane) * 17 + w * 4 + k] = acc[g][k];
    __syncthreads();

    { // softmax over m + phi -> LDS (256 (g,i) pairs, one per thread)
        int g = t >> 6, i = t & 63;
        const float* row = &buf[(g * IC + i) * 17];
        float v[16], mx = -1e30f;
#pragma unroll
        for (int m = 0; m < OC; m++) { v[m] = row[m]; mx = fmaxf(mx, v[m]); }
        float sum = 0.f;
#pragma unroll
        for (int m = 0; m < OC; m++) { v[m] = expf(v[m] - mx); sum += v[m]; }
        float inv = 1.0f / sum;
        float a2 = 0.f;
#pragma unroll
        for (int m = 0; m < OC; m++) a2 += v[m] * inv * cb[i * OC + m];
        phs[g][i] = fa[(size_t)(b0 + g) * IC + i] * (a2 - db[i]);
    }
    __syncthreads();

    { // fused kS: s[b] = sum_i phi[b][i]*tF[b][i][:], wave per b
        const int ig = lane >> 4, hq = lane & 15;
        const int b = b0 + w;
        const float4* tf4 = (const float4*)(tF + ((size_t)b * 64 + ig * 16) * 64) + hq;
        float4 a = make_float4(0.f, 0.f, 0.f, 0.f);
#pragma unroll
        for (int k = 0; k < 16; k++) {
            float p = phs[w][ig * 16 + k];
            float4 v = tf4[k * 16];
            a.x += p * v.x; a.y += p * v.y; a.z += p * v.z; a.w += p * v.w;
        }
#pragma unroll
        for (int k = 16; k <= 32; k <<= 1) {
            a.x += __shfl_xor(a.x, k); a.y += __shfl_xor(a.y, k);
            a.z += __shfl_xor(a.z, k); a.w += __shfl_xor(a.w, k);
        }
        if (ig == 0)
            ((float4*)(s + (size_t)b * 64))[hq] = a;
    }
}

// ---------------------------------------------------------------------------
extern "C" void kernel_launch(void* const* d_in, const int* in_sizes, int n_in,
                              void* d_out, int out_size, void* d_ws, size_t ws_size,
                              hipStream_t stream)
{
    const float* x    = (const float*)d_in[0];
    const float* W_A  = (const float*)d_in[1];
    const float* B_A  = (const float*)d_in[2];
    const float* W_F1 = (const float*)d_in[3];
    const float* W_F2 = (const float*)d_in[4];
    const float* B_F2 = (const float*)d_in[5];
    const float* W_G1 = (const float*)d_in[6];
    const float* W_G2 = (const float*)d_in[7];
    const float* B_G2 = (const float*)d_in[8];
    const float* gam  = (const float*)d_in[9];
    const float* bet  = (const float*)d_in[10];
    const float* W_S  = (const float*)d_in[11];
    const float* B_S  = (const float*)d_in[12];
    const float* bu   = (const float*)d_in[13];
    const float* bi_  = (const float*)d_in[14];

    float* ws   = (float*)d_ws;
    float* tF   = ws;                          // 16777216
    float* xq   = tF + 16777216;               // 16777216
    float* fa   = xq + 16777216;               // 262144
    float* phi  = fa + 262144;                 // 262144
    float* s    = phi + 262144;                // 262144
    float* xhat = s + 262144;                  // 4194304
    float* WSt2 = xhat + 4194304;              // 65536
    unsigned short* W1h = (unsigned short*)(WSt2 + 65536); // 65536 ushort = 32768 f
    unsigned short* W1l = W1h + 65536;
    unsigned short* W2h = W1l + 65536;
    unsigned short* W2l = W2h + 65536;
    float* BSt  = (float*)(W2l + 65536);       // 1024
    float* cb   = BSt + 1024;                  // 1024
    float* db   = cb + 1024;                   // 64
    float* out  = (float*)d_out;

    kF1<<<6400, 256, 0, stream>>>(W_F2, W_S, B_S, bu, bi_, W_G1, W_G2, W_F1,
                                  x, W_A, B_A,
                                  WSt2, W1h, W1l, W2h, W2l,
                                  BSt, cb, db, xq, fa, phi, tF);
    kS<<<1024, 256, 0, stream>>>(phi, tF, s);
    for (int it = 0; it < 3; ++it) {
        kXG<<<dim3(64, 16), 256, 0, stream>>>(s, W1h, W1l, B_F2, W2h, W2l, B_G2,
                                              gam, bet, xhat, out, it == 2 ? 1 : 0);
        if (it < 2)
            kC<<<1024, 256, 0, stream>>>(xq, xhat, WSt2, BSt, cb, db, fa, tF, s);
    }
}

// Round 10
// 274.013 us; speedup vs baseline: 1.0099x; 1.0099x over previous
//
#include <hip/hip_runtime.h>
#include <math.h>

#define IC 64
#define OC 16
#define DIM 64

typedef __attribute__((ext_vector_type(8))) short bf16x8;
typedef __attribute__((ext_vector_type(4))) float f32x4;

__device__ __forceinline__ unsigned short f2bf(float f) { // RNE float->bf16
    unsigned int b = __float_as_uint(f);
    b += 0x7fffu + ((b >> 16) & 1u);
    return (unsigned short)(b >> 16);
}
__device__ __forceinline__ float bf2f(unsigned short h) {
    return __uint_as_float(((unsigned int)h) << 16);
}

// ---------------------------------------------------------------------------
// kF1: fused {setup | kT | kA}. Blocks 0..255 setup, 256..2303 kT, 2304..6399
// kA (btile = ba&63, i = ba>>6). No cross-role dependencies inside the launch.
// R7 form (60.2 us measured). R9's B-panel XOR swizzle REVERTED: conflicts
// 3.93M->2.88M but dur 60->68 us — swizzle address VALU on the staging-bound
// kA role cost more than the (HBM-hidden) conflicts. Evidence list:
//  - cooperative kLoop grid-sync fusion: launch rejected, no output  (R8)
//  - B-panel 16B-slot swizzle: +8 us (VALU-bound staging)            (R9)
// ---------------------------------------------------------------------------
__global__ __launch_bounds__(256, 4)
void kF1(const float* __restrict__ W_F2, const float* __restrict__ W_S,
         const float* __restrict__ B_S, const float* __restrict__ bu,
         const float* __restrict__ bi_, const float* __restrict__ W_G1,
         const float* __restrict__ W_G2, const float* __restrict__ W_F1,
         const float* __restrict__ x, const float* __restrict__ W_A,
         const float* __restrict__ B_A,
         float* __restrict__ WSt2,
         unsigned short* __restrict__ W1h, unsigned short* __restrict__ W1l,
         unsigned short* __restrict__ W2h, unsigned short* __restrict__ W2l,
         float* __restrict__ BSt, float* __restrict__ cb, float* __restrict__ db,
         float* __restrict__ xq, float* __restrict__ fa, float* __restrict__ phi,
         float* __restrict__ tF)
{
    __shared__ __align__(16) unsigned char raw[36864];
    const int bx = blockIdx.x;
    const int t = threadIdx.x;

    if (bx < 256) { // ---- setup role ----
        int e = bx * 256 + t; // 0..65535
        { // W1: B^T of W_F2 panel, bf16 hi/lo
            int h = e >> 10, m = (e >> 6) & 15, d = e & 63;
            float v = W_F2[((size_t)m * 64 + h) * 64 + d];
            unsigned short hh = f2bf(v);
            size_t o = ((size_t)m * 64 + d) * 64 + h;
            W1h[o] = hh; W1l[o] = f2bf(v - bf2f(hh));
        }
        {
            int m = e >> 12, fo = (e >> 8) & 15, i = (e >> 2) & 63, fi = e & 3;
            WSt2[e] = W_S[((size_t)i * 16 + m) * 64 + fo * 4 + fi];
        }
        { // WG12[m][d][f] computed locally, stored transposed as W2[m][f][d]
            int m = e >> 12, d = (e >> 6) & 63, f = e & 63;
            const float* g1 = W_G1 + d * 64;
            const float* g2 = W_G2 + (size_t)m * 4096 + f;
            float a = 0.f;
#pragma unroll 8
            for (int h = 0; h < 64; h++) a += g1[h] * g2[h * 64];
            unsigned short hh = f2bf(a);
            size_t o = ((size_t)m * 64 + f) * 64 + d;
            W2h[o] = hh; W2l[o] = f2bf(a - bf2f(hh));
        }
        if (e < 1024) {
            int m = e >> 6, i = e & 63;
            BSt[e] = B_S[i * 16 + m];
            cb[e] = bu[e] + bi_[e];
        }
        if (e < 64) {
            float sd = 0.f;
            for (int m = 0; m < 16; m++) sd += bi_[e * 16 + m];
            db[e] = sd;
        }
        return;
    }

    if (bx < 2304) { // ---- kT role: x pass -> xq; fa/phi0 ----
        float* Xs = (float*)raw; // [2*64*65] = 33280 B
        const int blk = bx - 256;

        const float4* x4 = (const float4*)x;
#pragma unroll
        for (int s = 0; s < 8; s++) { // stage 2 batch rows, 1KB/instr coalesced
            int p = s * 256 + t;
            float4 v = x4[(size_t)blk * 2048 + p];
            int b = p >> 10, i = (p >> 4) & 63, fo = p & 15;
            float* row = &Xs[(b * 64 + i) * 65 + fo * 4];
            row[0] = v.x; row[1] = v.y; row[2] = v.z; row[3] = v.w;
        }
        __syncthreads();

        const int lane = t & 63, w = t >> 6;
#pragma unroll
        for (int s = 0; s < 8; s++) { // xq: lane=i, coalesced 1KB writes
            int idx = s * 4 + w;
            int b = idx >> 4, fo = idx & 15;
            const float* row = &Xs[(b * 64 + lane) * 65 + fo * 4];
            ((float4*)xq)[((size_t)(blk * 2 + b) * 16 + fo) * 64 + lane] =
                make_float4(row[0], row[1], row[2], row[3]);
        }

        { // fa/phi: pair p=(b,i), half h sums 32 f's
            int p = t >> 1, h = t & 1;
            int b = p >> 6, i = p & 63;
            const float* row = &Xs[(b * 64 + i) * 65 + h * 32];
            const float* wa = W_A + i * 64 + h * 32;
            float v = 0.f;
#pragma unroll
            for (int j = 0; j < 32; j++) v += row[j] * wa[j];
            v += __shfl_xor(v, 1);
            if (h == 0) {
                // eb[i] recomputed locally (bu/bi_ are L1/L2-hot, 8 KB total)
                float sc = 0.f, sd = 0.f;
                for (int m = 0; m < 16; m++) {
                    float vu = bu[i * 16 + m], vi = bi_[i * 16 + m];
                    sc += vu + vi; sd += vi;
                }
                float ebi = sc * (1.0f / 16.0f) - sd;
                float ae = v * 0.125f + B_A[i];
                float fv = 1.0f / (1.0f + expf(-ae));
                size_t o = (size_t)(blk * 2 + b) * 64 + i;
                fa[o] = fv;
                phi[o] = fv * ebi;
            }
        }
        return;
    }

    // ---- kA role (MFMA bf16x3): tF[b][i][h] = (x[b][i][:] @ W_F1[i]) * 0.125
    {
        unsigned short* Ah = (unsigned short*)raw; // [64][72] hi
        unsigned short* Al = Ah + 64 * 72;         // lo
        unsigned short* Bh = Al + 64 * 72;         // B^T hi
        unsigned short* Bl = Bh + 64 * 72;         // B^T lo
        const int ba = bx - 2304;
        const int b0 = (ba & 63) * 64;
        const int i = ba >> 6;
        const int bl = t >> 2, q = t & 3;

        { // stage X rows -> Ah/Al (split); W_F1 -> Bh/Bl (transpose+split)
            const float* src = x + ((size_t)(b0 + bl) * IC + i) * DIM + q * 4;
#pragma unroll
            for (int j4 = 0; j4 < 4; j4++) {
                float4 v = *(const float4*)(src + j4 * 16);
                int f = q * 4 + j4 * 16;
                float vv[4] = {v.x, v.y, v.z, v.w};
                ushort4 h4, l4;
                unsigned short hh;
                hh = f2bf(vv[0]); h4.x = hh; l4.x = f2bf(vv[0] - bf2f(hh));
                hh = f2bf(vv[1]); h4.y = hh; l4.y = f2bf(vv[1] - bf2f(hh));
                hh = f2bf(vv[2]); h4.z = hh; l4.z = f2bf(vv[2] - bf2f(hh));
                hh = f2bf(vv[3]); h4.w = hh; l4.w = f2bf(vv[3] - bf2f(hh));
                *(ushort4*)&Ah[bl * 72 + f] = h4;
                *(ushort4*)&Al[bl * 72 + f] = l4;
            }
            const float* wsrc = W_F1 + ((size_t)i * DIM + bl) * DIM + q * 4;
#pragma unroll
            for (int j4 = 0; j4 < 4; j4++) {
                float4 v = *(const float4*)(wsrc + j4 * 16);
                int h0 = q * 4 + j4 * 16;
                float vv[4] = {v.x, v.y, v.z, v.w};
#pragma unroll
                for (int c = 0; c < 4; c++) {
                    unsigned short hh = f2bf(vv[c]);
                    Bh[(h0 + c) * 72 + bl] = hh;
                    Bl[(h0 + c) * 72 + bl] = f2bf(vv[c] - bf2f(hh));
                }
            }
        }
        __syncthreads();

        const int w = t >> 6, lane = t & 63;
        const int fm = lane & 15, fq = lane >> 4;
        const int r0 = w * 16;
        f32x4 acc[4];
#pragma unroll
        for (int nt = 0; nt < 4; nt++) {
            acc[nt][0] = 0.f; acc[nt][1] = 0.f; acc[nt][2] = 0.f; acc[nt][3] = 0.f;
        }

#pragma unroll
        for (int ks = 0; ks < 2; ks++) {
            const int kk = ks * 32 + fq * 8;
            bf16x8 ah = *(const bf16x8*)&Ah[(r0 + fm) * 72 + kk];
            bf16x8 al = *(const bf16x8*)&Al[(r0 + fm) * 72 + kk];
#pragma unroll
            for (int nt = 0; nt < 4; nt++) {
                bf16x8 bh = *(const bf16x8*)&Bh[(nt * 16 + fm) * 72 + kk];
                bf16x8 bl2 = *(const bf16x8*)&Bl[(nt * 16 + fm) * 72 + kk];
                acc[nt] = __builtin_amdgcn_mfma_f32_16x16x32_bf16(ah, bh, acc[nt], 0, 0, 0);
                acc[nt] = __builtin_amdgcn_mfma_f32_16x16x32_bf16(ah, bl2, acc[nt], 0, 0, 0);
                acc[nt] = __builtin_amdgcn_mfma_f32_16x16x32_bf16(al, bh, acc[nt], 0, 0, 0);
            }
        }

#pragma unroll
        for (int nt = 0; nt < 4; nt++)
#pragma unroll
            for (int j = 0; j < 4; j++) {
                int row = r0 + fq * 4 + j;
                int col = nt * 16 + fm;
                tF[((size_t)(b0 + row) * IC + i) * DIM + col] = acc[nt][j] * 0.125f;
            }
    }
}

// ---------------------------------------------------------------------------
// kS: s[b][h] = sum_i phi[b][i] * tF[b][i][h].  1024 blocks, wave per b.
// (iteration-0 only; later iterations fused into kC)
// ---------------------------------------------------------------------------
__global__ __launch_bounds__(256, 4)
void kS(const float* __restrict__ phi, const float* __restrict__ tF,
        float* __restrict__ s)
{
    __shared__ float ph[4 * 64];
    const int t = threadIdx.x;
    const int b0 = blockIdx.x * 4;
    ph[t] = phi[(size_t)b0 * 64 + t];
    __syncthreads();

    const int w = t >> 6, lane = t & 63;
    const int ig = lane >> 4, hq = lane & 15;
    const int b = b0 + w;
    const float4* tf4 = (const float4*)(tF + ((size_t)b * 64 + ig * 16) * 64) + hq;
    float4 a = make_float4(0.f, 0.f, 0.f, 0.f);
#pragma unroll
    for (int k = 0; k < 16; k++) {
        float p = ph[w * 64 + ig * 16 + k];
        float4 v = tf4[k * 16];
        a.x += p * v.x; a.y += p * v.y; a.z += p * v.z; a.w += p * v.w;
    }
#pragma unroll
    for (int k = 16; k <= 32; k <<= 1) {
        a.x += __shfl_xor(a.x, k); a.y += __shfl_xor(a.y, k);
        a.z += __shfl_xor(a.z, k); a.w += __shfl_xor(a.w, k);
    }
    if (ig == 0)
        ((float4*)(s + (size_t)b * 64))[hq] = a;
}

// ---------------------------------------------------------------------------
// kXG (MFMA bf16x3): per (b-tile 64, m): two chained GEMMs.
//  GEMM1: x_out = s @ W_F2[m] + B_F2[m]  (A=s split on the fly, B=W1 panel)
//  (last: write out, exit)  LN in-register (quad shfl), xnorm->LDS bf16 split
//  GEMM2: xhat = xnorm @ WG12[m] + B_G2[m]  (B=W2 panel)
// LDS: A(hi/lo) + B(hi/lo), both reused across the two GEMMs. 36.9 KB.
// ---------------------------------------------------------------------------
__global__ __launch_bounds__(256, 4)
void kXG(const float* __restrict__ s,
         const unsigned short* __restrict__ W1h, const unsigned short* __restrict__ W1l,
         const float* __restrict__ B_F2,
         const unsigned short* __restrict__ W2h, const unsigned short* __restrict__ W2l,
         const float* __restrict__ B_G2,
         const float* __restrict__ gam, const float* __restrict__ bet,
         float* __restrict__ xhat, float* __restrict__ out, const int last)
{
    __shared__ unsigned short Ah[64][72], Al[64][72]; // s then xnorm (hi/lo)
    __shared__ unsigned short Bh[64][72], Bl[64][72]; // W1^T then W2^T panels
    const int b0 = blockIdx.x * 64;
    const int m = blockIdx.y;
    const int t = threadIdx.x;
    const int bl = t >> 2, q = t & 3;

    { // stage s rows -> Ah/Al (split), W1 panel -> Bh/Bl (copy)
        const float* src = s + (size_t)(b0 + bl) * DIM + q * 16;
#pragma unroll
        for (int j4 = 0; j4 < 4; j4++) {
            float4 v = ((const float4*)src)[j4];
            int f = q * 16 + j4 * 4;
            float vv[4] = {v.x, v.y, v.z, v.w};
            ushort4 h4, l4;
            unsigned short hh;
            hh = f2bf(vv[0]); h4.x = hh; l4.x = f2bf(vv[0] - bf2f(hh));
            hh = f2bf(vv[1]); h4.y = hh; l4.y = f2bf(vv[1] - bf2f(hh));
            hh = f2bf(vv[2]); h4.z = hh; l4.z = f2bf(vv[2] - bf2f(hh));
            hh = f2bf(vv[3]); h4.w = hh; l4.w = f2bf(vv[3] - bf2f(hh));
            *(ushort4*)&Ah[bl][f] = h4;
            *(ushort4*)&Al[bl][f] = l4;
        }
        const size_t wo = ((size_t)m * 64 + bl) * 64 + q * 16;
#pragma unroll
        for (int part = 0; part < 2; part++) {
            *(uint4*)&Bh[bl][q * 16 + part * 8] = *(const uint4*)(W1h + wo + part * 8);
            *(uint4*)&Bl[bl][q * 16 + part * 8] = *(const uint4*)(W1l + wo + part * 8);
        }
    }
    __syncthreads();

    const int w = t >> 6, lane = t & 63;
    const int fm = lane & 15, fq = lane >> 4;
    const int r0 = w * 16;
    f32x4 acc[4];
#pragma unroll
    for (int nt = 0; nt < 4; nt++) {
        acc[nt][0] = 0.f; acc[nt][1] = 0.f; acc[nt][2] = 0.f; acc[nt][3] = 0.f;
    }
#pragma unroll
    for (int ks = 0; ks < 2; ks++) {
        const int kk = ks * 32 + fq * 8;
        bf16x8 ah = *(const bf16x8*)&Ah[r0 + fm][kk];
        bf16x8 al = *(const bf16x8*)&Al[r0 + fm][kk];
#pragma unroll
        for (int nt = 0; nt < 4; nt++) {
            bf16x8 bh = *(const bf16x8*)&Bh[nt * 16 + fm][kk];
            bf16x8 bl2 = *(const bf16x8*)&Bl[nt * 16 + fm][kk];
            acc[nt] = __builtin_amdgcn_mfma_f32_16x16x32_bf16(ah, bh, acc[nt], 0, 0, 0);
            acc[nt] = __builtin_amdgcn_mfma_f32_16x16x32_bf16(ah, bl2, acc[nt], 0, 0, 0);
            acc[nt] = __builtin_amdgcn_mfma_f32_16x16x32_bf16(al, bh, acc[nt], 0, 0, 0);
        }
    }
#pragma unroll
    for (int nt = 0; nt < 4; nt++) { // + B_F2[m]
        float bf = B_F2[m * DIM + nt * 16 + fm];
#pragma unroll
        for (int j = 0; j < 4; j++) acc[nt][j] += bf;
    }

    if (last) { // final x_out
#pragma unroll
        for (int nt = 0; nt < 4; nt++)
#pragma unroll
            for (int j = 0; j < 4; j++) {
                int row = r0 + fq * 4 + j;
                out[((size_t)(b0 + row) * OC + m) * DIM + nt * 16 + fm] = acc[nt][j];
            }
        return;
    }

    { // LayerNorm: row = b = r0+fq*4+j lives across 16 fm-lanes x 4 regs
        float g4[4], b4[4];
#pragma unroll
        for (int nt = 0; nt < 4; nt++) {
            g4[nt] = gam[nt * 16 + fm];
            b4[nt] = bet[nt * 16 + fm];
        }
#pragma unroll
        for (int j = 0; j < 4; j++) {
            float sum = acc[0][j] + acc[1][j] + acc[2][j] + acc[3][j];
            float sq = acc[0][j] * acc[0][j] + acc[1][j] * acc[1][j] +
                       acc[2][j] * acc[2][j] + acc[3][j] * acc[3][j];
#pragma unroll
            for (int k = 1; k <= 8; k <<= 1) {
                sum += __shfl_xor(sum, k);
                sq  += __shfl_xor(sq, k);
            }
            float mu = sum * (1.0f / 64.0f);
            float var = sq * (1.0f / 64.0f) - mu * mu;
            float rs = 1.0f / sqrtf(var + 1e-5f);
#pragma unroll
            for (int nt = 0; nt < 4; nt++)
                acc[nt][j] = (acc[nt][j] - mu) * rs * g4[nt] + b4[nt];
        }
    }
    __syncthreads(); // GEMM1 LDS reads complete before overwrite

    { // A <- xnorm (split, C-layout scatter); B <- W2 panel
#pragma unroll
        for (int nt = 0; nt < 4; nt++)
#pragma unroll
            for (int j = 0; j < 4; j++) {
                float v = acc[nt][j];
                unsigned short hh = f2bf(v);
                int row = r0 + fq * 4 + j, col = nt * 16 + fm;
                Ah[row][col] = hh;
                Al[row][col] = f2bf(v - bf2f(hh));
            }
        const size_t wo = ((size_t)m * 64 + bl) * 64 + q * 16;
#pragma unroll
        for (int part = 0; part < 2; part++) {
            *(uint4*)&Bh[bl][q * 16 + part * 8] = *(const uint4*)(W2h + wo + part * 8);
            *(uint4*)&Bl[bl][q * 16 + part * 8] = *(const uint4*)(W2l + wo + part * 8);
        }
    }
    __syncthreads();

    f32x4 xh[4];
#pragma unroll
    for (int nt = 0; nt < 4; nt++) {
        float bg = B_G2[m * DIM + nt * 16 + fm];
        xh[nt][0] = bg; xh[nt][1] = bg; xh[nt][2] = bg; xh[nt][3] = bg;
    }
#pragma unroll
    for (int ks = 0; ks < 2; ks++) {
        const int kk = ks * 32 + fq * 8;
        bf16x8 ah = *(const bf16x8*)&Ah[r0 + fm][kk];
        bf16x8 al = *(const bf16x8*)&Al[r0 + fm][kk];
#pragma unroll
        for (int nt = 0; nt < 4; nt++) {
            bf16x8 bh = *(const bf16x8*)&Bh[nt * 16 + fm][kk];
            bf16x8 bl2 = *(const bf16x8*)&Bl[nt * 16 + fm][kk];
            xh[nt] = __builtin_amdgcn_mfma_f32_16x16x32_bf16(ah, bh, xh[nt], 0, 0, 0);
            xh[nt] = __builtin_amdgcn_mfma_f32_16x16x32_bf16(ah, bl2, xh[nt], 0, 0, 0);
            xh[nt] = __builtin_amdgcn_mfma_f32_16x16x32_bf16(al, bh, xh[nt], 0, 0, 0);
        }
    }
#pragma unroll
    for (int nt = 0; nt < 4; nt++)
#pragma unroll
        for (int j = 0; j < 4; j++) {
            int row = r0 + fq * 4 + j;
            xhat[((size_t)(b0 + row) * OC + m) * DIM + nt * 16 + fm] = xh[nt][j];
        }
}

// ---------------------------------------------------------------------------
// kC: consistency + softmax + phi + NEXT-ITER s (fused kS). 4 b/block, 1024
// blocks, 256 threads — the measured equilibrium (39.6 us).
// Perturbations measured and rejected (the evidence list):
//  - 512t/4b (waves split g): +17% VMEM instrs -> 45.1us          (R1)
//  - scalar-pipe xhat (s_load): K$ thrash, FETCH +8MB -> 52.4us   (R2)
//  - 256t/2b x 2048 blocks: L2 thrash, FETCH 250MB -> 142us       (R3)
//  - uniform-addr global vector loads for xhat: latency-exposed,
//    VALUBusy 28% -> 60.4us                                       (R6)
//  - cooperative grid-sync fusion: launch rejected, no output     (R8)
// ---------------------------------------------------------------------------
__global__ __launch_bounds__(256, 4)
void kC(const float* __restrict__ xq, const float* __restrict__ xhat,
        const float* __restrict__ WSt2, const float* __restrict__ BSt,
        const float* __restrict__ cb, const float* __restrict__ db,
        const float* __restrict__ fa, const float* __restrict__ tF,
        float* __restrict__ s)
{
    __shared__ float buf[4 * 64 * 17]; // xhat view (4096) -> cons view (g*64+i)*17+m
    __shared__ float phs[4][64];
    const int b0 = blockIdx.x * 4;
    const int t = threadIdx.x;
    const int w = t >> 6, lane = t & 63;

    { // stage xhat[b0..b0+4): 4096 floats
        const float4* src = (const float4*)(xhat + (size_t)b0 * OC * DIM);
        float4* dst = (float4*)buf;
#pragma unroll
        for (int j = 0; j < 4; j++) dst[t + j * 256] = src[t + j * 256];
    }
    __syncthreads();

    float acc[4][4];
#pragma unroll
    for (int k = 0; k < 4; k++) {
        float bs = BSt[(w * 4 + k) * IC + lane];
#pragma unroll
        for (int g = 0; g < 4; g++) acc[g][k] = bs;
    }

    const float4* xq4 = (const float4*)xq;
    for (int fc = 0; fc < 64; fc += 8) {
        const int fo = fc >> 2;
        float wreg[4][8];
#pragma unroll
        for (int k = 0; k < 4; k++) {
            int m = w * 4 + k;
#pragma unroll
            for (int q2 = 0; q2 < 2; q2++) {
                float4 v = *(const float4*)&WSt2[(((size_t)m * 16 + fo + q2) * IC + lane) * 4];
                wreg[k][q2 * 4 + 0] = v.x; wreg[k][q2 * 4 + 1] = v.y;
                wreg[k][q2 * 4 + 2] = v.z; wreg[k][q2 * 4 + 3] = v.w;
            }
        }
#pragma unroll
        for (int g = 0; g < 4; g++) {
            float xr[8];
#pragma unroll
            for (int q2 = 0; q2 < 2; q2++) { // coalesced 1KB/instr
                float4 v = xq4[((size_t)(b0 + g) * 16 + fo + q2) * 64 + lane];
                xr[q2 * 4 + 0] = v.x; xr[q2 * 4 + 1] = v.y;
                xr[q2 * 4 + 2] = v.z; xr[q2 * 4 + 3] = v.w;
            }
#pragma unroll
            for (int k = 0; k < 4; k++) {
                int m = w * 4 + k;
                const float* hp = &buf[(g * OC + m) * DIM + fc];
                float hr[8];
#pragma unroll
                for (int q2 = 0; q2 < 2; q2++) { // same-addr broadcast reads
                    float4 v = *(const float4*)(hp + q2 * 4);
                    hr[q2 * 4 + 0] = v.x; hr[q2 * 4 + 1] = v.y;
                    hr[q2 * 4 + 2] = v.z; hr[q2 * 4 + 3] = v.w;
                }
#pragma unroll
                for (int ff = 0; ff < 8; ff++)
                    acc[g][k] += xr[ff] * hr[ff] * wreg[k][ff];
            }
        }
    }
    __syncthreads(); // all xhat reads done before overwrite
#pragma unroll
    for (int g = 0; g < 4; g++)
#pragma unroll
        for (int k = 0; k < 4; k++)
            buf[(g * IC + lane) * 17 + w * 4 + k] = acc[g][k];
    __syncthreads();

    { // softmax over m + phi -> LDS (256 (g,i) pairs, one per thread)
        int g = t >> 6, i = t & 63;
        const float* row = &buf[(g * IC + i) * 17];
        float v[16], mx = -1e30f;
#pragma unroll
        for (int m = 0; m < OC; m++) { v[m] = row[m]; mx = fmaxf(mx, v[m]); }
        float sum = 0.f;
#pragma unroll
        for (int m = 0; m < OC; m++) { v[m] = expf(v[m] - mx); sum += v[m]; }
        float inv = 1.0f / sum;
        float a2 = 0.f;
#pragma unroll
        for (int m = 0; m < OC; m++) a2 += v[m] * inv * cb[i * OC + m];
        phs[g][i] = fa[(size_t)(b0 + g) * IC + i] * (a2 - db[i]);
    }
    __syncthreads();

    { // fused kS: s[b] = sum_i phi[b][i]*tF[b][i][:], wave per b
        const int ig = lane >> 4, hq = lane & 15;
        const int b = b0 + w;
        const float4* tf4 = (const float4*)(tF + ((size_t)b * 64 + ig * 16) * 64) + hq;
        float4 a = make_float4(0.f, 0.f, 0.f, 0.f);
#pragma unroll
        for (int k = 0; k < 16; k++) {
            float p = phs[w][ig * 16 + k];
            float4 v = tf4[k * 16];
            a.x += p * v.x; a.y += p * v.y; a.z += p * v.z; a.w += p * v.w;
        }
#pragma unroll
        for (int k = 16; k <= 32; k <<= 1) {
            a.x += __shfl_xor(a.x, k); a.y += __shfl_xor(a.y, k);
            a.z += __shfl_xor(a.z, k); a.w += __shfl_xor(a.w, k);
        }
        if (ig == 0)
            ((float4*)(s + (size_t)b * 64))[hq] = a;
    }
}

// ---------------------------------------------------------------------------
extern "C" void kernel_launch(void* const* d_in, const int* in_sizes, int n_in,
                              void* d_out, int out_size, void* d_ws, size_t ws_size,
                              hipStream_t stream)
{
    const float* x    = (const float*)d_in[0];
    const float* W_A  = (const float*)d_in[1];
    const float* B_A  = (const float*)d_in[2];
    const float* W_F1 = (const float*)d_in[3];
    const float* W_F2 = (const float*)d_in[4];
    const float* B_F2 = (const float*)d_in[5];
    const float* W_G1 = (const float*)d_in[6];
    const float* W_G2 = (const float*)d_in[7];
    const float* B_G2 = (const float*)d_in[8];
    const float* gam  = (const float*)d_in[9];
    const float* bet  = (const float*)d_in[10];
    const float* W_S  = (const float*)d_in[11];
    const float* B_S  = (const float*)d_in[12];
    const float* bu   = (const float*)d_in[13];
    const float* bi_  = (const float*)d_in[14];

    float* ws   = (float*)d_ws;
    float* tF   = ws;                          // 16777216
    float* xq   = tF + 16777216;               // 16777216
    float* fa   = xq + 16777216;               // 262144
    float* phi  = fa + 262144;                 // 262144
    float* s    = phi + 262144;                // 262144
    float* xhat = s + 262144;                  // 4194304
    float* WSt2 = xhat + 4194304;              // 65536
    unsigned short* W1h = (unsigned short*)(WSt2 + 65536); // 65536 ushort = 32768 f
    unsigned short* W1l = W1h + 65536;
    unsigned short* W2h = W1l + 65536;
    unsigned short* W2l = W2h + 65536;
    float* BSt  = (float*)(W2l + 65536);       // 1024
    float* cb   = BSt + 1024;                  // 1024
    float* db   = cb + 1024;                   // 64
    float* out  = (float*)d_out;

    kF1<<<6400, 256, 0, stream>>>(W_F2, W_S, B_S, bu, bi_, W_G1, W_G2, W_F1,
                                  x, W_A, B_A,
                                  WSt2, W1h, W1l, W2h, W2l,
                                  BSt, cb, db, xq, fa, phi, tF);
    kS<<<1024, 256, 0, stream>>>(phi, tF, s);
    for (int it = 0; it < 3; ++it) {
        kXG<<<dim3(64, 16), 256, 0, stream>>>(s, W1h, W1l, B_F2, W2h, W2l, B_G2,
                                              gam, bet, xhat, out, it == 2 ? 1 : 0);
        if (it < 2)
            kC<<<1024, 256, 0, stream>>>(xq, xhat, WSt2, BSt, cb, db, fa, tF, s);
    }
}